// Round 9
// baseline (274.498 us; speedup 1.0000x reference)
//
#include <hip/hip_runtime.h>
#include <math.h>

#define IN_DIM 128
#define HID 64
#define NEG_SLOPE 0.2f
#define CHUNK 4096
#define GCAP 6144

typedef __attribute__((ext_vector_type(8))) short bf16x8;
typedef __attribute__((ext_vector_type(4))) float f32x4;
typedef __attribute__((ext_vector_type(2))) float v2f;

__device__ __forceinline__ float wmax(float v){
  #pragma unroll
  for (int o = 32; o > 0; o >>= 1) v = fmaxf(v, __shfl_xor(v, o));
  return v;
}
__device__ __forceinline__ float wsum(float v){
  #pragma unroll
  for (int o = 32; o > 0; o >>= 1) v += __shfl_xor(v, o);
  return v;
}
__device__ __forceinline__ unsigned short f2bf(float f){
  union { float f; unsigned u; } v; v.f = f;
  unsigned r = v.u + 0x7fffu + ((v.u >> 16) & 1u);
  return (unsigned short)(r >> 16);
}
__device__ __forceinline__ float bl(unsigned u){
  union { unsigned u; float f; } v; v.u = u << 16; return v.f;
}
__device__ __forceinline__ float bh(unsigned u){
  union { unsigned u; float f; } v; v.u = u & 0xffff0000u; return v.f;
}
__device__ __forceinline__ v2f up2(unsigned u){
  v2f r; r[0] = bl(u); r[1] = bh(u); return r;
}

// race-safe in-place inclusive scan of sh[0..255], 256 threads
__device__ __forceinline__ void incl_scan256(int* sh, int tid){
  #pragma unroll
  for (int off = 1; off < 256; off <<= 1){
    int v = sh[tid];
    if (tid >= off) v += sh[tid - off];
    __syncthreads();
    sh[tid] = v;
    __syncthreads();
  }
}

// ---------- CSR build (sort-based) ----------

// Merged prep: blocks [0,NBLK) pack edges + coarse histogram;
// blocks [NBLK, NBLK+80) convert W1/W2 to bf16 transposed; seed row_ptr[N]=E.
__global__ __launch_bounds__(256) void prep(const int* __restrict__ ei, int E, int NBLK,
                                            unsigned* __restrict__ packed,
                                            int* __restrict__ binCnt,
                                            const float* __restrict__ W1,
                                            const float* __restrict__ W2,
                                            unsigned short* __restrict__ W1t,
                                            unsigned short* __restrict__ W2t,
                                            int* __restrict__ row_ptr, int N){
  int tid = threadIdx.x;
  if ((int)blockIdx.x < NBLK){
    __shared__ int lh[256];
    lh[tid] = 0; __syncthreads();
    int base = blockIdx.x * CHUNK;
    #pragma unroll
    for (int j = 0; j < CHUNK / 256; j++){
      int e = base + j * 256 + tid;
      if (e < E){
        unsigned s = (unsigned)ei[e];
        unsigned d = (unsigned)ei[E + e];
        packed[e] = (d << 16) | s;
        atomicAdd(&lh[d >> 8], 1);
      }
    }
    __syncthreads();
    if (lh[tid] > 0) atomicAdd(&binCnt[tid], lh[tid]);
  } else {
    int t = (blockIdx.x - NBLK) * 256 + tid;
    if (t < 128 * 128){
      int n = t >> 7, k = t & 127;
      W1t[n * 128 + k] = f2bf(W1[k * 128 + n]);
    }
    int t2 = t - 128 * 128;
    if (t2 >= 0 && t2 < 64 * 64){
      int n = t2 >> 6, k = t2 & 63;
      W2t[n * 64 + k] = f2bf(W2[k * 64 + n]);
    }
    if (t == 0) row_ptr[N] = E;
  }
}

// bin edges into coarse-bin-grouped array; bin bases computed by inline scan
__global__ __launch_bounds__(256) void scatter_bins(const unsigned* __restrict__ packed, int E,
                                                    const int* __restrict__ binCnt,
                                                    int* __restrict__ binOff,
                                                    unsigned* __restrict__ binned){
  __shared__ int bc[256], lh[256], lbase[256], gpos[256], lcur[256];
  __shared__ unsigned buf[CHUNK];
  int tid = threadIdx.x;
  int cg = binCnt[tid];
  bc[tid] = cg;
  lh[tid] = 0;
  __syncthreads();
  incl_scan256(bc, tid);
  int binBase_t = bc[tid] - cg;     // exclusive scan value for bin==tid
  int base = blockIdx.x * CHUNK;
  int rem = E - base;
  unsigned v[CHUNK / 256];
  #pragma unroll
  for (int j = 0; j < CHUNK / 256; j++){
    int i = j * 256 + tid;
    if (i < rem){ v[j] = packed[base + i]; atomicAdd(&lh[v[j] >> 24], 1); }
  }
  __syncthreads();
  lbase[tid] = lh[tid]; __syncthreads();
  incl_scan256(lbase, tid);
  int myExcl = tid ? lbase[tid - 1] : 0;
  __syncthreads();
  lbase[tid] = myExcl;
  lcur[tid] = myExcl;
  if (lh[tid] > 0) gpos[tid] = binBase_t + atomicAdd(&binOff[tid], lh[tid]);
  __syncthreads();
  #pragma unroll
  for (int j = 0; j < CHUNK / 256; j++){
    int i = j * 256 + tid;
    if (i < rem){
      int b = v[j] >> 24;
      int p = atomicAdd(&lcur[b], 1);
      buf[p] = v[j];
    }
  }
  __syncthreads();
  int cn = rem < CHUNK ? rem : CHUNK;
  for (int i = tid; i < cn; i += 256){
    unsigned u = buf[i];
    int b = u >> 24;
    binned[gpos[b] + (i - lbase[b])] = u;
  }
}

// per coarse bin: LDS counting sort by dst&255 -> sorted edges + CSR row_ptr
__global__ __launch_bounds__(256) void group_sort(const unsigned* __restrict__ binned,
                                                  const int* __restrict__ binCnt,
                                                  unsigned* __restrict__ sorted,
                                                  int* __restrict__ row_ptr, int N){
  __shared__ unsigned A[GCAP], B[GCAP];
  __shared__ int sc[256], h2[256], rs[256], cur[256];
  int g = blockIdx.x, tid = threadIdx.x;
  int cg = binCnt[tid];
  sc[tid] = cg;
  h2[tid] = 0;
  __syncthreads();
  incl_scan256(sc, tid);
  int base = sc[g] - binCnt[g];     // broadcast read: exclusive base of bin g
  int cnt = binCnt[g]; if (cnt > GCAP) cnt = GCAP;
  __syncthreads();
  for (int i = tid; i < cnt; i += 256){
    unsigned u = binned[base + i];
    A[i] = u;
    atomicAdd(&h2[(u >> 16) & 255], 1);
  }
  __syncthreads();
  rs[tid] = h2[tid]; __syncthreads();
  incl_scan256(rs, tid);
  int excl = tid ? rs[tid - 1] : 0;
  __syncthreads();
  rs[tid] = excl; cur[tid] = excl;
  int d = g * 256 + tid;
  if (d < N) row_ptr[d] = base + excl;
  __syncthreads();
  for (int i = tid; i < cnt; i += 256){
    unsigned u = A[i];
    int p = atomicAdd(&cur[(u >> 16) & 255], 1);
    B[p] = u;
  }
  __syncthreads();
  for (int i = tid; i < cnt; i += 256)
    sorted[base + i] = B[i];
}

// ---------- layer-1 GEMM (MFMA bf16, M-tile 128, 512 threads) ----------

template<int K, int NC, int HEADS>
__global__ __launch_bounds__(512) void gemm_mfma(const float* __restrict__ X,
    const unsigned short* __restrict__ Wt, const float* __restrict__ asrc,
    const float* __restrict__ adst, unsigned short* __restrict__ Hb,
    float* __restrict__ aa, int n_rows)
{
  constexpr int MT = 128;
  constexpr int KP = K + 8;
  constexpr int CP = NC + 4;
  constexpr int MF = MT / 16;
  constexpr int NFt = NC / 16;
  constexpr int WPN = 8 / NFt;
  constexpr int MFW = MF / WPN;
  constexpr unsigned SM1 = (unsigned)(MT + NC) * KP * 2;
  constexpr unsigned SM2 = (unsigned)MT * CP * 4;
  __shared__ char smem[SM1 > SM2 ? SM1 : SM2];
  unsigned short* xa = (unsigned short*)smem;
  unsigned short* wl = xa + MT * KP;
  int tid = threadIdx.x;
  int n0 = blockIdx.x * MT;

  for (int idx = tid; idx < MT * (K / 4); idx += 512){
    int n = idx / (K / 4), k4 = idx % (K / 4);
    float4 v = make_float4(0.f, 0.f, 0.f, 0.f);
    if (n0 + n < n_rows) v = *(const float4*)&X[(size_t)(n0 + n) * K + k4 * 4];
    ushort4 pk; pk.x = f2bf(v.x); pk.y = f2bf(v.y); pk.z = f2bf(v.z); pk.w = f2bf(v.w);
    *(ushort4*)&xa[n * KP + k4 * 4] = pk;
  }
  for (int idx = tid; idx < NC * (K / 8); idx += 512){
    int n = idx / (K / 8), k8 = idx % (K / 8);
    uint4 v = *(const uint4*)&Wt[(size_t)n * K + k8 * 8];
    *(uint4*)&wl[n * KP + k8 * 8] = v;
  }
  __syncthreads();

  int lane = tid & 63, w = tid >> 6;
  int m = lane & 15, q = lane >> 4;
  int nf = w % NFt;
  int mseg = w / NFt;
  f32x4 acc[MFW];
  #pragma unroll
  for (int i = 0; i < MFW; i++)
    #pragma unroll
    for (int r = 0; r < 4; r++) acc[i][r] = 0.f;

  #pragma unroll
  for (int ks = 0; ks < K / 32; ks++){
    bf16x8 bg = *(const bf16x8*)&wl[(nf * 16 + m) * KP + ks * 32 + q * 8];
    #pragma unroll
    for (int i = 0; i < MFW; i++){
      bf16x8 af = *(const bf16x8*)&xa[((mseg * MFW + i) * 16 + m) * KP + ks * 32 + q * 8];
      acc[i] = __builtin_amdgcn_mfma_f32_16x16x32_bf16(af, bg, acc[i], 0, 0, 0);
    }
  }
  __syncthreads();
  float* C = (float*)smem;
  #pragma unroll
  for (int i = 0; i < MFW; i++)
    #pragma unroll
    for (int r = 0; r < 4; r++)
      C[((mseg * MFW + i) * 16 + q * 4 + r) * CP + nf * 16 + m] = acc[i][r];
  __syncthreads();

  constexpr int CH = NC / 4;
  int row = tid >> 2;
  int c0 = (tid & 3) * CH;
  int n = n0 + row;
  int head = (HEADS == 2) ? (c0 >> 6) : 0;
  float s_p = 0.f, d_p = 0.f;
  unsigned short hb[CH];
  #pragma unroll
  for (int c = 0; c < CH; c += 4){
    f32x4 v = *(const f32x4*)&C[row * CP + c0 + c];
    #pragma unroll
    for (int u = 0; u < 4; u++){
      int ch = (c0 + c + u) & 63;
      s_p += v[u] * asrc[head * 64 + ch];
      d_p += v[u] * adst[head * 64 + ch];
      hb[c + u] = f2bf(v[u]);
    }
  }
  if (n < n_rows){
    #pragma unroll
    for (int c = 0; c < CH; c += 8){
      uint4 pk;
      pk.x = (unsigned)hb[c]     | ((unsigned)hb[c + 1] << 16);
      pk.y = (unsigned)hb[c + 2] | ((unsigned)hb[c + 3] << 16);
      pk.z = (unsigned)hb[c + 4] | ((unsigned)hb[c + 5] << 16);
      pk.w = (unsigned)hb[c + 6] | ((unsigned)hb[c + 7] << 16);
      *(uint4*)&Hb[(size_t)n * NC + c0 + c] = pk;
    }
  }
  s_p += __shfl_xor(s_p, 1);
  d_p += __shfl_xor(d_p, 1);
  if (HEADS == 2){
    if ((tid & 1) == 0 && n < n_rows){
      aa[(size_t)n * 4 + head]     = s_p;
      aa[(size_t)n * 4 + 2 + head] = d_p;
    }
  } else {
    s_p += __shfl_xor(s_p, 2);
    d_p += __shfl_xor(d_p, 2);
    if ((tid & 3) == 0 && n < n_rows){
      aa[(size_t)n * 2]     = s_p;
      aa[(size_t)n * 2 + 1] = d_p;
    }
  }
}

// ---------- fused: layer-1 softmax+aggregation + layer-2 GEMM ----------
// One wave (64 threads) per block; 16 destinations per block.
// Phase A: per dst, round-5 agg1 body; ELU'd x1 row -> LDS bf16 tile [16][72].
// Phase B: 16x64 @ 64x64 MFMA (A from LDS, B-frags from global W2t).
// Epilogue: C->LDS, bf16 h2b write + fused layer-2 attention coefs (aa2).
__global__ __launch_bounds__(64) void agg1_gemm2(const int* __restrict__ row_ptr,
    const unsigned* __restrict__ sorted, const float* __restrict__ aa,
    const unsigned short* __restrict__ h1b, const float* __restrict__ b1,
    const unsigned short* __restrict__ W2t, const float* __restrict__ asrc2,
    const float* __restrict__ adst2, unsigned short* __restrict__ h2b,
    float* __restrict__ aa2, int n_nodes)
{
  __shared__ unsigned short xt[16 * 72];   // bf16 x1 tile, pitch 72
  __shared__ float Cl[16 * 68];            // fp32 C tile, pitch 68
  int lane = threadIdx.x;
  int d0 = blockIdx.x * 16;

  // ---- phase A: aggregate 16 destination rows ----
  int g = lane >> 4, c = lane & 15;
  for (int jd = 0; jd < 16; jd++){
    int d = d0 + jd;
    if (d >= n_nodes) break;
    int rp0 = row_ptr[d];
    int deg = row_ptr[d + 1] - rp0;
    float2 adv = *(const float2*)&aa[d * 4 + 2];
    int s = -1;
    if (lane < deg) s = (int)(sorted[rp0 + lane] & 0xffffu);
    else if (lane == deg) s = d;
    float e0 = -INFINITY, e1 = -INFINITY;
    if (s >= 0){
      float2 asv = *(const float2*)&aa[s * 4];
      float t0 = asv.x + adv.x;
      float t1 = asv.y + adv.y;
      e0 = t0 >= 0.f ? t0 : NEG_SLOPE * t0;
      e1 = t1 >= 0.f ? t1 : NEG_SLOPE * t1;
    }
    float m0 = wmax(e0), m1 = wmax(e1);
    float p0 = (s >= 0) ? __expf(e0 - m0) : 0.f;
    float p1 = (s >= 0) ? __expf(e1 - m1) : 0.f;
    float al0 = p0 / (wsum(p0) + 1e-16f);
    float al1 = p1 / (wsum(p1) + 1e-16f);
    int ne = deg + 1;
    v2f acc[4] = {{0.f,0.f},{0.f,0.f},{0.f,0.f},{0.f,0.f}};
    #pragma unroll 2
    for (int j0 = 0; j0 < ne; j0 += 4){
      int j = j0 + g;
      int sj = __shfl(s, j);
      float a0 = __shfl(al0, j);
      float a1 = __shfl(al1, j);
      if (j < ne){
        uint4 v = ((const uint4*)(h1b + (size_t)sj * 128))[c];
        float a = (c < 8) ? a0 : a1;
        v2f av = {a, a};
        acc[0] = av * up2(v.x) + acc[0];
        acc[1] = av * up2(v.y) + acc[1];
        acc[2] = av * up2(v.z) + acc[2];
        acc[3] = av * up2(v.w) + acc[3];
      }
    }
    float accf[8] = {acc[0][0], acc[0][1], acc[1][0], acc[1][1],
                     acc[2][0], acc[2][1], acc[3][0], acc[3][1]};
    #pragma unroll
    for (int i = 0; i < 8; i++){
      accf[i] += __shfl_xor(accf[i], 16);
      accf[i] += __shfl_xor(accf[i], 32);
    }
    float outv[8];
    #pragma unroll
    for (int i = 0; i < 8; i++){
      float o = __shfl_xor(accf[i], 8);
      outv[i] = 0.5f * (accf[i] + o);   // head mean
    }
    if (g == 0 && c < 8){
      unsigned short rb[8];
      #pragma unroll
      for (int i = 0; i < 8; i++){
        float v = outv[i] + b1[c * 8 + i];
        rb[i] = f2bf(v > 0.f ? v : expm1f(v));   // ELU, bf16
      }
      uint4 pk;
      pk.x = (unsigned)rb[0] | ((unsigned)rb[1] << 16);
      pk.y = (unsigned)rb[2] | ((unsigned)rb[3] << 16);
      pk.z = (unsigned)rb[4] | ((unsigned)rb[5] << 16);
      pk.w = (unsigned)rb[6] | ((unsigned)rb[7] << 16);
      *(uint4*)&xt[jd * 72 + c * 8] = pk;
    }
  }
  __syncthreads();

  // ---- phase B: h2 = x1_tile @ W2 (16x64 @ 64x64) ----
  int m = lane & 15, q = lane >> 4;
  f32x4 cacc[4];
  #pragma unroll
  for (int nf = 0; nf < 4; nf++)
    #pragma unroll
    for (int r = 0; r < 4; r++) cacc[nf][r] = 0.f;
  #pragma unroll
  for (int ks = 0; ks < 2; ks++){
    bf16x8 af = *(const bf16x8*)&xt[m * 72 + ks * 32 + q * 8];
    #pragma unroll
    for (int nf = 0; nf < 4; nf++){
      bf16x8 bg = *(const bf16x8*)&W2t[(size_t)(nf * 16 + m) * 64 + ks * 32 + q * 8];
      cacc[nf] = __builtin_amdgcn_mfma_f32_16x16x32_bf16(af, bg, cacc[nf], 0, 0, 0);
    }
  }
  #pragma unroll
  for (int nf = 0; nf < 4; nf++)
    #pragma unroll
    for (int r = 0; r < 4; r++)
      Cl[(q * 4 + r) * 68 + nf * 16 + m] = cacc[nf][r];
  __syncthreads();

  // ---- epilogue: bf16 h2b + layer-2 attention coefs ----
  int row = lane >> 2, qt = lane & 3;
  int n = d0 + row;
  float sp = 0.f, dp = 0.f;
  unsigned pk[8];
  #pragma unroll
  for (int c2 = 0; c2 < 8; c2++){
    int ch = qt * 16 + c2 * 2;
    float v0 = Cl[row * 68 + ch];
    float v1 = Cl[row * 68 + ch + 1];
    sp += v0 * asrc2[ch] + v1 * asrc2[ch + 1];
    dp += v0 * adst2[ch] + v1 * adst2[ch + 1];
    pk[c2] = (unsigned)f2bf(v0) | ((unsigned)f2bf(v1) << 16);
  }
  if (n < n_nodes){
    uint4* dst = (uint4*)&h2b[(size_t)n * 64 + qt * 16];
    dst[0] = make_uint4(pk[0], pk[1], pk[2], pk[3]);
    dst[1] = make_uint4(pk[4], pk[5], pk[6], pk[7]);
  }
  sp += __shfl_xor(sp, 1); dp += __shfl_xor(dp, 1);
  sp += __shfl_xor(sp, 2); dp += __shfl_xor(dp, 2);
  if (qt == 0 && n < n_nodes){
    aa2[(size_t)n * 2]     = sp;
    aa2[(size_t)n * 2 + 1] = dp;
  }
}

// ---------- layer-2 softmax + aggregation (unchanged round-5 form) ----------

__global__ void agg_layer2(const int* __restrict__ row_ptr, const unsigned* __restrict__ sorted,
                           const float* __restrict__ aa, const unsigned short* __restrict__ h2b,
                           const float* __restrict__ b2, float* __restrict__ out, int n_nodes){
  int d = (blockIdx.x * blockDim.x + threadIdx.x) >> 6;
  int lane = threadIdx.x & 63;
  if (d >= n_nodes) return;
  int rp0 = row_ptr[d];
  int deg = row_ptr[d + 1] - rp0;
  float ad = aa[d * 2 + 1];
  int s = -1;
  if (lane < deg) s = (int)(sorted[rp0 + lane] & 0xffffu);
  else if (lane == deg) s = d;
  float e = -INFINITY;
  if (s >= 0){
    float t = aa[s * 2 + 0] + ad;
    e = t >= 0.f ? t : NEG_SLOPE * t;
  }
  float m = wmax(e);
  float p = (s >= 0) ? __expf(e - m) : 0.f;
  float al = p / (wsum(p) + 1e-16f);
  int ne = deg + 1;
  int g = lane >> 3, c = lane & 7;
  v2f acc[4] = {{0.f,0.f},{0.f,0.f},{0.f,0.f},{0.f,0.f}};
  #pragma unroll 2
  for (int j0 = 0; j0 < ne; j0 += 8){
    int j = j0 + g;
    int sj = __shfl(s, j);
    float a = __shfl(al, j);
    if (j < ne){
      uint4 v = ((const uint4*)(h2b + (size_t)sj * 64))[c];
      v2f av = {a, a};
      acc[0] = av * up2(v.x) + acc[0];
      acc[1] = av * up2(v.y) + acc[1];
      acc[2] = av * up2(v.z) + acc[2];
      acc[3] = av * up2(v.w) + acc[3];
    }
  }
  float accf[8] = {acc[0][0], acc[0][1], acc[1][0], acc[1][1],
                   acc[2][0], acc[2][1], acc[3][0], acc[3][1]};
  #pragma unroll
  for (int i = 0; i < 8; i++){
    accf[i] += __shfl_xor(accf[i], 8);
    accf[i] += __shfl_xor(accf[i], 16);
    accf[i] += __shfl_xor(accf[i], 32);
  }
  if (lane < 8){
    float r[8];
    #pragma unroll
    for (int i = 0; i < 8; i++) r[i] = accf[i] + b2[lane * 8 + i];
    float* q = &out[(size_t)d * 64 + lane * 8];
    *(float4*)q       = make_float4(r[0], r[1], r[2], r[3]);
    *(float4*)(q + 4) = make_float4(r[4], r[5], r[6], r[7]);
  }
}

extern "C" void kernel_launch(void* const* d_in, const int* in_sizes, int n_in,
                              void* d_out, int out_size, void* d_ws, size_t ws_size,
                              hipStream_t stream){
  const float* x     = (const float*)d_in[0];
  const int*   ei    = (const int*)d_in[1];
  const float* W1    = (const float*)d_in[2];
  const float* asrc1 = (const float*)d_in[3];
  const float* adst1 = (const float*)d_in[4];
  const float* b1    = (const float*)d_in[5];
  const float* W2    = (const float*)d_in[6];
  const float* asrc2 = (const float*)d_in[7];
  const float* adst2 = (const float*)d_in[8];
  const float* b2    = (const float*)d_in[9];
  float* out = (float*)d_out;
  int N = in_sizes[0] / IN_DIM;   // 50000 (< 65536 for 16-bit packing)
  int E = in_sizes[1] / 2;
  int NG = (N + 255) >> 8;
  int NBLK = (E + CHUNK - 1) / CHUNK;
  int ngrp = (N + 3) / 4;

  char* p = (char*)d_ws;
  unsigned short* h1b = (unsigned short*)p;  p += (size_t)N * 128 * 2;
  unsigned short* h2b = (unsigned short*)p;  p += (size_t)N * 64 * 2;
  float* aa1 = (float*)p;                    p += (size_t)N * 4 * 4;
  float* aa2 = (float*)p;                    p += (size_t)N * 2 * 4;
  unsigned* packed = (unsigned*)p;           p += (size_t)E * 4;
  unsigned* binned = (unsigned*)p;           p += (size_t)E * 4;
  unsigned* sorted = (unsigned*)p;           p += (size_t)E * 4;
  int* row_ptr   = (int*)p;                  p += (size_t)(N + 1) * 4;
  int* binCnt    = (int*)p;                  p += 256 * 4;
  int* binOff    = (int*)p;                  p += 256 * 4;
  unsigned short* W1t = (unsigned short*)p;  p += 128 * 128 * 2;
  unsigned short* W2t = (unsigned short*)p;

  hipMemsetAsync(binCnt, 0, 512 * sizeof(int), stream);   // binCnt + binOff
  prep<<<NBLK + 80, 256, 0, stream>>>(ei, E, NBLK, packed, binCnt,
                                      W1, W2, W1t, W2t, row_ptr, N);
  scatter_bins<<<NBLK, 256, 0, stream>>>(packed, E, binCnt, binOff, binned);
  group_sort<<<NG, 256, 0, stream>>>(binned, binCnt, sorted, row_ptr, N);
  gemm_mfma<128, 128, 2><<<(N + 127) / 128, 512, 0, stream>>>(
      x, W1t, asrc1, adst1, h1b, aa1, N);
  agg1_gemm2<<<(N + 15) / 16, 64, 0, stream>>>(
      row_ptr, sorted, aa1, h1b, b1, W2t, asrc2, adst2, h2b, aa2, N);
  agg_layer2<<<ngrp, 256, 0, stream>>>(row_ptr, sorted, aa2, h2b, b2, out, N);
}

// Round 10
// 242.104 us; speedup vs baseline: 1.1338x; 1.1338x over previous
//
#include <hip/hip_runtime.h>
#include <math.h>

#define IN_DIM 128
#define HID 64
#define NEG_SLOPE 0.2f
#define CHUNK 4096
#define GCAP 6144

typedef __attribute__((ext_vector_type(8))) short bf16x8;
typedef __attribute__((ext_vector_type(4))) float f32x4;
typedef __attribute__((ext_vector_type(2))) float v2f;

__device__ __forceinline__ float wmax(float v){
  #pragma unroll
  for (int o = 32; o > 0; o >>= 1) v = fmaxf(v, __shfl_xor(v, o));
  return v;
}
__device__ __forceinline__ float wsum(float v){
  #pragma unroll
  for (int o = 32; o > 0; o >>= 1) v += __shfl_xor(v, o);
  return v;
}
__device__ __forceinline__ unsigned short f2bf(float f){
  union { float f; unsigned u; } v; v.f = f;
  unsigned r = v.u + 0x7fffu + ((v.u >> 16) & 1u);
  return (unsigned short)(r >> 16);
}
__device__ __forceinline__ float bl(unsigned u){
  union { unsigned u; float f; } v; v.u = u << 16; return v.f;
}
__device__ __forceinline__ float bh(unsigned u){
  union { unsigned u; float f; } v; v.u = u & 0xffff0000u; return v.f;
}
__device__ __forceinline__ v2f up2(unsigned u){
  v2f r; r[0] = bl(u); r[1] = bh(u); return r;
}

// race-safe in-place inclusive scan of sh[0..255], 256 threads
__device__ __forceinline__ void incl_scan256(int* sh, int tid){
  #pragma unroll
  for (int off = 1; off < 256; off <<= 1){
    int v = sh[tid];
    if (tid >= off) v += sh[tid - off];
    __syncthreads();
    sh[tid] = v;
    __syncthreads();
  }
}

// ---------- CSR build (sort-based) ----------

// Merged prep: blocks [0,NBLK) pack edges + coarse histogram;
// blocks [NBLK, NBLK+80) convert W1/W2 to bf16 transposed; seed row_ptr[N]=E.
__global__ __launch_bounds__(256) void prep(const int* __restrict__ ei, int E, int NBLK,
                                            unsigned* __restrict__ packed,
                                            int* __restrict__ binCnt,
                                            const float* __restrict__ W1,
                                            const float* __restrict__ W2,
                                            unsigned short* __restrict__ W1t,
                                            unsigned short* __restrict__ W2t,
                                            int* __restrict__ row_ptr, int N){
  int tid = threadIdx.x;
  if ((int)blockIdx.x < NBLK){
    __shared__ int lh[256];
    lh[tid] = 0; __syncthreads();
    int base = blockIdx.x * CHUNK;
    #pragma unroll
    for (int j = 0; j < CHUNK / 256; j++){
      int e = base + j * 256 + tid;
      if (e < E){
        unsigned s = (unsigned)ei[e];
        unsigned d = (unsigned)ei[E + e];
        packed[e] = (d << 16) | s;
        atomicAdd(&lh[d >> 8], 1);
      }
    }
    __syncthreads();
    if (lh[tid] > 0) atomicAdd(&binCnt[tid], lh[tid]);
  } else {
    int t = (blockIdx.x - NBLK) * 256 + tid;
    if (t < 128 * 128){
      int n = t >> 7, k = t & 127;
      W1t[n * 128 + k] = f2bf(W1[k * 128 + n]);
    }
    int t2 = t - 128 * 128;
    if (t2 >= 0 && t2 < 64 * 64){
      int n = t2 >> 6, k = t2 & 63;
      W2t[n * 64 + k] = f2bf(W2[k * 64 + n]);
    }
    if (t == 0) row_ptr[N] = E;
  }
}

// bin edges into coarse-bin-grouped array; bin bases computed by inline scan
__global__ __launch_bounds__(256) void scatter_bins(const unsigned* __restrict__ packed, int E,
                                                    const int* __restrict__ binCnt,
                                                    int* __restrict__ binOff,
                                                    unsigned* __restrict__ binned){
  __shared__ int bc[256], lh[256], lbase[256], gpos[256], lcur[256];
  __shared__ unsigned buf[CHUNK];
  int tid = threadIdx.x;
  int cg = binCnt[tid];
  bc[tid] = cg;
  lh[tid] = 0;
  __syncthreads();
  incl_scan256(bc, tid);
  int binBase_t = bc[tid] - cg;     // exclusive scan value for bin==tid
  int base = blockIdx.x * CHUNK;
  int rem = E - base;
  unsigned v[CHUNK / 256];
  #pragma unroll
  for (int j = 0; j < CHUNK / 256; j++){
    int i = j * 256 + tid;
    if (i < rem){ v[j] = packed[base + i]; atomicAdd(&lh[v[j] >> 24], 1); }
  }
  __syncthreads();
  lbase[tid] = lh[tid]; __syncthreads();
  incl_scan256(lbase, tid);
  int myExcl = tid ? lbase[tid - 1] : 0;
  __syncthreads();
  lbase[tid] = myExcl;
  lcur[tid] = myExcl;
  if (lh[tid] > 0) gpos[tid] = binBase_t + atomicAdd(&binOff[tid], lh[tid]);
  __syncthreads();
  #pragma unroll
  for (int j = 0; j < CHUNK / 256; j++){
    int i = j * 256 + tid;
    if (i < rem){
      int b = v[j] >> 24;
      int p = atomicAdd(&lcur[b], 1);
      buf[p] = v[j];
    }
  }
  __syncthreads();
  int cn = rem < CHUNK ? rem : CHUNK;
  for (int i = tid; i < cn; i += 256){
    unsigned u = buf[i];
    int b = u >> 24;
    binned[gpos[b] + (i - lbase[b])] = u;
  }
}

// per coarse bin: LDS counting sort by dst&255 -> sorted edges + CSR row_ptr
__global__ __launch_bounds__(256) void group_sort(const unsigned* __restrict__ binned,
                                                  const int* __restrict__ binCnt,
                                                  unsigned* __restrict__ sorted,
                                                  int* __restrict__ row_ptr, int N){
  __shared__ unsigned A[GCAP], B[GCAP];
  __shared__ int sc[256], h2[256], rs[256], cur[256];
  int g = blockIdx.x, tid = threadIdx.x;
  int cg = binCnt[tid];
  sc[tid] = cg;
  h2[tid] = 0;
  __syncthreads();
  incl_scan256(sc, tid);
  int base = sc[g] - binCnt[g];     // broadcast read: exclusive base of bin g
  int cnt = binCnt[g]; if (cnt > GCAP) cnt = GCAP;
  __syncthreads();
  for (int i = tid; i < cnt; i += 256){
    unsigned u = binned[base + i];
    A[i] = u;
    atomicAdd(&h2[(u >> 16) & 255], 1);
  }
  __syncthreads();
  rs[tid] = h2[tid]; __syncthreads();
  incl_scan256(rs, tid);
  int excl = tid ? rs[tid - 1] : 0;
  __syncthreads();
  rs[tid] = excl; cur[tid] = excl;
  int d = g * 256 + tid;
  if (d < N) row_ptr[d] = base + excl;
  __syncthreads();
  for (int i = tid; i < cnt; i += 256){
    unsigned u = A[i];
    int p = atomicAdd(&cur[(u >> 16) & 255], 1);
    B[p] = u;
  }
  __syncthreads();
  for (int i = tid; i < cnt; i += 256)
    sorted[base + i] = B[i];
}

// ---------- layer-1 GEMM (MFMA bf16, M-tile 128, 512 threads) ----------

template<int K, int NC, int HEADS>
__global__ __launch_bounds__(512) void gemm_mfma(const float* __restrict__ X,
    const unsigned short* __restrict__ Wt, const float* __restrict__ asrc,
    const float* __restrict__ adst, unsigned short* __restrict__ Hb,
    float* __restrict__ aa, int n_rows)
{
  constexpr int MT = 128;
  constexpr int KP = K + 8;
  constexpr int CP = NC + 4;
  constexpr int MF = MT / 16;
  constexpr int NFt = NC / 16;
  constexpr int WPN = 8 / NFt;
  constexpr int MFW = MF / WPN;
  constexpr unsigned SM1 = (unsigned)(MT + NC) * KP * 2;
  constexpr unsigned SM2 = (unsigned)MT * CP * 4;
  __shared__ char smem[SM1 > SM2 ? SM1 : SM2];
  unsigned short* xa = (unsigned short*)smem;
  unsigned short* wl = xa + MT * KP;
  int tid = threadIdx.x;
  int n0 = blockIdx.x * MT;

  for (int idx = tid; idx < MT * (K / 4); idx += 512){
    int n = idx / (K / 4), k4 = idx % (K / 4);
    float4 v = make_float4(0.f, 0.f, 0.f, 0.f);
    if (n0 + n < n_rows) v = *(const float4*)&X[(size_t)(n0 + n) * K + k4 * 4];
    ushort4 pk; pk.x = f2bf(v.x); pk.y = f2bf(v.y); pk.z = f2bf(v.z); pk.w = f2bf(v.w);
    *(ushort4*)&xa[n * KP + k4 * 4] = pk;
  }
  for (int idx = tid; idx < NC * (K / 8); idx += 512){
    int n = idx / (K / 8), k8 = idx % (K / 8);
    uint4 v = *(const uint4*)&Wt[(size_t)n * K + k8 * 8];
    *(uint4*)&wl[n * KP + k8 * 8] = v;
  }
  __syncthreads();

  int lane = tid & 63, w = tid >> 6;
  int m = lane & 15, q = lane >> 4;
  int nf = w % NFt;
  int mseg = w / NFt;
  f32x4 acc[MFW];
  #pragma unroll
  for (int i = 0; i < MFW; i++)
    #pragma unroll
    for (int r = 0; r < 4; r++) acc[i][r] = 0.f;

  #pragma unroll
  for (int ks = 0; ks < K / 32; ks++){
    bf16x8 bg = *(const bf16x8*)&wl[(nf * 16 + m) * KP + ks * 32 + q * 8];
    #pragma unroll
    for (int i = 0; i < MFW; i++){
      bf16x8 af = *(const bf16x8*)&xa[((mseg * MFW + i) * 16 + m) * KP + ks * 32 + q * 8];
      acc[i] = __builtin_amdgcn_mfma_f32_16x16x32_bf16(af, bg, acc[i], 0, 0, 0);
    }
  }
  __syncthreads();
  float* C = (float*)smem;
  #pragma unroll
  for (int i = 0; i < MFW; i++)
    #pragma unroll
    for (int r = 0; r < 4; r++)
      C[((mseg * MFW + i) * 16 + q * 4 + r) * CP + nf * 16 + m] = acc[i][r];
  __syncthreads();

  constexpr int CH = NC / 4;
  int row = tid >> 2;
  int c0 = (tid & 3) * CH;
  int n = n0 + row;
  int head = (HEADS == 2) ? (c0 >> 6) : 0;
  float s_p = 0.f, d_p = 0.f;
  unsigned short hb[CH];
  #pragma unroll
  for (int c = 0; c < CH; c += 4){
    f32x4 v = *(const f32x4*)&C[row * CP + c0 + c];
    #pragma unroll
    for (int u = 0; u < 4; u++){
      int ch = (c0 + c + u) & 63;
      s_p += v[u] * asrc[head * 64 + ch];
      d_p += v[u] * adst[head * 64 + ch];
      hb[c + u] = f2bf(v[u]);
    }
  }
  if (n < n_rows){
    #pragma unroll
    for (int c = 0; c < CH; c += 8){
      uint4 pk;
      pk.x = (unsigned)hb[c]     | ((unsigned)hb[c + 1] << 16);
      pk.y = (unsigned)hb[c + 2] | ((unsigned)hb[c + 3] << 16);
      pk.z = (unsigned)hb[c + 4] | ((unsigned)hb[c + 5] << 16);
      pk.w = (unsigned)hb[c + 6] | ((unsigned)hb[c + 7] << 16);
      *(uint4*)&Hb[(size_t)n * NC + c0 + c] = pk;
    }
  }
  s_p += __shfl_xor(s_p, 1);
  d_p += __shfl_xor(d_p, 1);
  if (HEADS == 2){
    if ((tid & 1) == 0 && n < n_rows){
      aa[(size_t)n * 4 + head]     = s_p;
      aa[(size_t)n * 4 + 2 + head] = d_p;
    }
  } else {
    s_p += __shfl_xor(s_p, 2);
    d_p += __shfl_xor(d_p, 2);
    if ((tid & 3) == 0 && n < n_rows){
      aa[(size_t)n * 2]     = s_p;
      aa[(size_t)n * 2 + 1] = d_p;
    }
  }
}

// ---------- fused: layer-1 softmax+aggregation + layer-2 GEMM ----------
// 256 threads (4 waves), 16 destinations per block (wave w: dsts 4w..4w+3).
// Phase A: per dst, round-5 agg1 body; ELU'd x1 row -> LDS bf16 tile [16][72].
// Phase B: 16x64 @ 64x64 MFMA; wave w computes output cols 16w..16w+15
//          (A from LDS, B-frag from global W2t — broadcast, L1-resident).
// Epilogue: C->LDS, bf16 h2b write + fused layer-2 attention coefs (aa2).
__global__ __launch_bounds__(256) void agg1_gemm2(const int* __restrict__ row_ptr,
    const unsigned* __restrict__ sorted, const float* __restrict__ aa,
    const unsigned short* __restrict__ h1b, const float* __restrict__ b1,
    const unsigned short* __restrict__ W2t, const float* __restrict__ asrc2,
    const float* __restrict__ adst2, unsigned short* __restrict__ h2b,
    float* __restrict__ aa2, int n_nodes)
{
  __shared__ unsigned short xt[16 * 72];   // bf16 x1 tile, pitch 72 (2-way banks: free)
  __shared__ float Cl[16 * 68];            // fp32 C tile, pitch 68
  int tid = threadIdx.x;
  int lane = tid & 63, w = tid >> 6;
  int d0 = blockIdx.x * 16;

  // ---- phase A: each wave aggregates 4 destination rows ----
  int g = lane >> 4, c = lane & 15;
  #pragma unroll
  for (int i4 = 0; i4 < 4; i4++){
    int jd = w * 4 + i4;
    int d = d0 + jd;
    if (d >= n_nodes) break;
    int rp0 = row_ptr[d];
    int deg = row_ptr[d + 1] - rp0;
    float2 adv = *(const float2*)&aa[d * 4 + 2];
    int s = -1;
    if (lane < deg) s = (int)(sorted[rp0 + lane] & 0xffffu);
    else if (lane == deg) s = d;
    float e0 = -INFINITY, e1 = -INFINITY;
    if (s >= 0){
      float2 asv = *(const float2*)&aa[s * 4];
      float t0 = asv.x + adv.x;
      float t1 = asv.y + adv.y;
      e0 = t0 >= 0.f ? t0 : NEG_SLOPE * t0;
      e1 = t1 >= 0.f ? t1 : NEG_SLOPE * t1;
    }
    float m0 = wmax(e0), m1 = wmax(e1);
    float p0 = (s >= 0) ? __expf(e0 - m0) : 0.f;
    float p1 = (s >= 0) ? __expf(e1 - m1) : 0.f;
    float al0 = p0 / (wsum(p0) + 1e-16f);
    float al1 = p1 / (wsum(p1) + 1e-16f);
    int ne = deg + 1;
    v2f acc[4] = {{0.f,0.f},{0.f,0.f},{0.f,0.f},{0.f,0.f}};
    #pragma unroll 2
    for (int j0 = 0; j0 < ne; j0 += 4){
      int j = j0 + g;
      int sj = __shfl(s, j);
      float a0 = __shfl(al0, j);
      float a1 = __shfl(al1, j);
      if (j < ne){
        uint4 v = ((const uint4*)(h1b + (size_t)sj * 128))[c];
        float a = (c < 8) ? a0 : a1;
        v2f av = {a, a};
        acc[0] = av * up2(v.x) + acc[0];
        acc[1] = av * up2(v.y) + acc[1];
        acc[2] = av * up2(v.z) + acc[2];
        acc[3] = av * up2(v.w) + acc[3];
      }
    }
    float accf[8] = {acc[0][0], acc[0][1], acc[1][0], acc[1][1],
                     acc[2][0], acc[2][1], acc[3][0], acc[3][1]};
    #pragma unroll
    for (int i = 0; i < 8; i++){
      accf[i] += __shfl_xor(accf[i], 16);
      accf[i] += __shfl_xor(accf[i], 32);
    }
    float outv[8];
    #pragma unroll
    for (int i = 0; i < 8; i++){
      float o = __shfl_xor(accf[i], 8);
      outv[i] = 0.5f * (accf[i] + o);   // head mean
    }
    if (g == 0 && c < 8){
      unsigned short rb[8];
      #pragma unroll
      for (int i = 0; i < 8; i++){
        float v = outv[i] + b1[c * 8 + i];
        rb[i] = f2bf(v > 0.f ? v : expm1f(v));   // ELU, bf16
      }
      uint4 pk;
      pk.x = (unsigned)rb[0] | ((unsigned)rb[1] << 16);
      pk.y = (unsigned)rb[2] | ((unsigned)rb[3] << 16);
      pk.z = (unsigned)rb[4] | ((unsigned)rb[5] << 16);
      pk.w = (unsigned)rb[6] | ((unsigned)rb[7] << 16);
      *(uint4*)&xt[jd * 72 + c * 8] = pk;
    }
  }
  __syncthreads();

  // ---- phase B: h2 = x1_tile @ W2; wave w -> output cols 16w..16w+15 ----
  int m = lane & 15, q = lane >> 4;
  f32x4 cacc;
  #pragma unroll
  for (int r = 0; r < 4; r++) cacc[r] = 0.f;
  #pragma unroll
  for (int ks = 0; ks < 2; ks++){
    bf16x8 af = *(const bf16x8*)&xt[m * 72 + ks * 32 + q * 8];
    bf16x8 bg = *(const bf16x8*)&W2t[(size_t)(w * 16 + m) * 64 + ks * 32 + q * 8];
    cacc = __builtin_amdgcn_mfma_f32_16x16x32_bf16(af, bg, cacc, 0, 0, 0);
  }
  #pragma unroll
  for (int r = 0; r < 4; r++)
    Cl[(q * 4 + r) * 68 + w * 16 + m] = cacc[r];
  __syncthreads();

  // ---- epilogue: bf16 h2b + layer-2 attention coefs ----
  // thread t: row r = t>>4 (16 rows), col group cg = t&15 (4 cols each);
  // same-row threads are 16 contiguous lanes -> shfl_xor 1,2,4,8 reduces.
  int r = tid >> 4, cg = tid & 15;
  int n = d0 + r;
  f32x4 v = *(const f32x4*)&Cl[r * 68 + cg * 4];
  float sp = 0.f, dp = 0.f;
  unsigned pk2[2];
  #pragma unroll
  for (int u = 0; u < 4; u++){
    int ch = cg * 4 + u;
    sp += v[u] * asrc2[ch];
    dp += v[u] * adst2[ch];
  }
  pk2[0] = (unsigned)f2bf(v[0]) | ((unsigned)f2bf(v[1]) << 16);
  pk2[1] = (unsigned)f2bf(v[2]) | ((unsigned)f2bf(v[3]) << 16);
  if (n < n_nodes)
    *(uint2*)&h2b[(size_t)n * 64 + cg * 4] = make_uint2(pk2[0], pk2[1]);
  sp += __shfl_xor(sp, 1); dp += __shfl_xor(dp, 1);
  sp += __shfl_xor(sp, 2); dp += __shfl_xor(dp, 2);
  sp += __shfl_xor(sp, 4); dp += __shfl_xor(dp, 4);
  sp += __shfl_xor(sp, 8); dp += __shfl_xor(dp, 8);
  if (cg == 0 && n < n_nodes){
    aa2[(size_t)n * 2]     = sp;
    aa2[(size_t)n * 2 + 1] = dp;
  }
}

// ---------- layer-2 softmax + aggregation (round-5 form) ----------

__global__ void agg_layer2(const int* __restrict__ row_ptr, const unsigned* __restrict__ sorted,
                           const float* __restrict__ aa, const unsigned short* __restrict__ h2b,
                           const float* __restrict__ b2, float* __restrict__ out, int n_nodes){
  int d = (blockIdx.x * blockDim.x + threadIdx.x) >> 6;
  int lane = threadIdx.x & 63;
  if (d >= n_nodes) return;
  int rp0 = row_ptr[d];
  int deg = row_ptr[d + 1] - rp0;
  float ad = aa[d * 2 + 1];
  int s = -1;
  if (lane < deg) s = (int)(sorted[rp0 + lane] & 0xffffu);
  else if (lane == deg) s = d;
  float e = -INFINITY;
  if (s >= 0){
    float t = aa[s * 2 + 0] + ad;
    e = t >= 0.f ? t : NEG_SLOPE * t;
  }
  float m = wmax(e);
  float p = (s >= 0) ? __expf(e - m) : 0.f;
  float al = p / (wsum(p) + 1e-16f);
  int ne = deg + 1;
  int g = lane >> 3, c = lane & 7;
  v2f acc[4] = {{0.f,0.f},{0.f,0.f},{0.f,0.f},{0.f,0.f}};
  #pragma unroll 2
  for (int j0 = 0; j0 < ne; j0 += 8){
    int j = j0 + g;
    int sj = __shfl(s, j);
    float a = __shfl(al, j);
    if (j < ne){
      uint4 v = ((const uint4*)(h2b + (size_t)sj * 64))[c];
      v2f av = {a, a};
      acc[0] = av * up2(v.x) + acc[0];
      acc[1] = av * up2(v.y) + acc[1];
      acc[2] = av * up2(v.z) + acc[2];
      acc[3] = av * up2(v.w) + acc[3];
    }
  }
  float accf[8] = {acc[0][0], acc[0][1], acc[1][0], acc[1][1],
                   acc[2][0], acc[2][1], acc[3][0], acc[3][1]};
  #pragma unroll
  for (int i = 0; i < 8; i++){
    accf[i] += __shfl_xor(accf[i], 8);
    accf[i] += __shfl_xor(accf[i], 16);
    accf[i] += __shfl_xor(accf[i], 32);
  }
  if (lane < 8){
    float r[8];
    #pragma unroll
    for (int i = 0; i < 8; i++) r[i] = accf[i] + b2[lane * 8 + i];
    float* q = &out[(size_t)d * 64 + lane * 8];
    *(float4*)q       = make_float4(r[0], r[1], r[2], r[3]);
    *(float4*)(q + 4) = make_float4(r[4], r[5], r[6], r[7]);
  }
}

extern "C" void kernel_launch(void* const* d_in, const int* in_sizes, int n_in,
                              void* d_out, int out_size, void* d_ws, size_t ws_size,
                              hipStream_t stream){
  const float* x     = (const float*)d_in[0];
  const int*   ei    = (const int*)d_in[1];
  const float* W1    = (const float*)d_in[2];
  const float* asrc1 = (const float*)d_in[3];
  const float* adst1 = (const float*)d_in[4];
  const float* b1    = (const float*)d_in[5];
  const float* W2    = (const float*)d_in[6];
  const float* asrc2 = (const float*)d_in[7];
  const float* adst2 = (const float*)d_in[8];
  const float* b2    = (const float*)d_in[9];
  float* out = (float*)d_out;
  int N = in_sizes[0] / IN_DIM;   // 50000 (< 65536 for 16-bit packing)
  int E = in_sizes[1] / 2;
  int NG = (N + 255) >> 8;
  int NBLK = (E + CHUNK - 1) / CHUNK;
  int ngrp = (N + 3) / 4;

  char* p = (char*)d_ws;
  unsigned short* h1b = (unsigned short*)p;  p += (size_t)N * 128 * 2;
  unsigned short* h2b = (unsigned short*)p;  p += (size_t)N * 64 * 2;
  float* aa1 = (float*)p;                    p += (size_t)N * 4 * 4;
  float* aa2 = (float*)p;                    p += (size_t)N * 2 * 4;
  unsigned* packed = (unsigned*)p;           p += (size_t)E * 4;
  unsigned* binned = (unsigned*)p;           p += (size_t)E * 4;
  unsigned* sorted = (unsigned*)p;           p += (size_t)E * 4;
  int* row_ptr   = (int*)p;                  p += (size_t)(N + 1) * 4;
  int* binCnt    = (int*)p;                  p += 256 * 4;
  int* binOff    = (int*)p;                  p += 256 * 4;
  unsigned short* W1t = (unsigned short*)p;  p += 128 * 128 * 2;
  unsigned short* W2t = (unsigned short*)p;

  hipMemsetAsync(binCnt, 0, 512 * sizeof(int), stream);   // binCnt + binOff
  prep<<<NBLK + 80, 256, 0, stream>>>(ei, E, NBLK, packed, binCnt,
                                      W1, W2, W1t, W2t, row_ptr, N);
  scatter_bins<<<NBLK, 256, 0, stream>>>(packed, E, binCnt, binOff, binned);
  group_sort<<<NG, 256, 0, stream>>>(binned, binCnt, sorted, row_ptr, N);
  gemm_mfma<128, 128, 2><<<(N + 127) / 128, 512, 0, stream>>>(
      x, W1t, asrc1, adst1, h1b, aa1, N);
  agg1_gemm2<<<(N + 15) / 16, 256, 0, stream>>>(
      row_ptr, sorted, aa1, h1b, b1, W2t, asrc2, adst2, h2b, aa2, N);
  agg_layer2<<<ngrp, 256, 0, stream>>>(row_ptr, sorted, aa2, h2b, b2, out, N);
}

// Round 11
// 235.648 us; speedup vs baseline: 1.1649x; 1.0274x over previous
//
#include <hip/hip_runtime.h>
#include <math.h>

#define IN_DIM 128
#define HID 64
#define NEG_SLOPE 0.2f
#define CHUNK 4096
#define GCAP 6144
#define SMEM_UNION 53248

typedef __attribute__((ext_vector_type(8))) short bf16x8;
typedef __attribute__((ext_vector_type(4))) float f32x4;
typedef __attribute__((ext_vector_type(2))) float v2f;

__device__ __forceinline__ float wmax(float v){
  #pragma unroll
  for (int o = 32; o > 0; o >>= 1) v = fmaxf(v, __shfl_xor(v, o));
  return v;
}
__device__ __forceinline__ float wsum(float v){
  #pragma unroll
  for (int o = 32; o > 0; o >>= 1) v += __shfl_xor(v, o);
  return v;
}
__device__ __forceinline__ unsigned short f2bf(float f){
  union { float f; unsigned u; } v; v.f = f;
  unsigned r = v.u + 0x7fffu + ((v.u >> 16) & 1u);
  return (unsigned short)(r >> 16);
}
__device__ __forceinline__ float bl(unsigned u){
  union { unsigned u; float f; } v; v.u = u << 16; return v.f;
}
__device__ __forceinline__ float bh(unsigned u){
  union { unsigned u; float f; } v; v.u = u & 0xffff0000u; return v.f;
}
__device__ __forceinline__ v2f up2(unsigned u){
  v2f r; r[0] = bl(u); r[1] = bh(u); return r;
}

// race-safe in-place inclusive scan of sh[0..255], 256 threads
__device__ __forceinline__ void incl_scan256(int* sh, int tid){
  #pragma unroll
  for (int off = 1; off < 256; off <<= 1){
    int v = sh[tid];
    if (tid >= off) v += sh[tid - off];
    __syncthreads();
    sh[tid] = v;
    __syncthreads();
  }
}

// ---------- CSR build: phase bodies (device fns over a shared smem union) ----------

__device__ void scatter_body(char* smem, const unsigned* __restrict__ packed, int E,
                             const int* __restrict__ binCnt, int* __restrict__ binOff,
                             unsigned* __restrict__ binned, int bx){
  int* ib = (int*)smem;
  int* bc = ib;           // 256
  int* lh = ib + 256;
  int* lbase = ib + 512;
  int* gpos = ib + 768;
  int* lcur = ib + 1024;
  unsigned* buf = (unsigned*)(ib + 1280);   // CHUNK
  int tid = threadIdx.x;
  int cg = binCnt[tid];
  bc[tid] = cg;
  lh[tid] = 0;
  __syncthreads();
  incl_scan256(bc, tid);
  int binBase_t = bc[tid] - cg;
  int base = bx * CHUNK;
  int rem = E - base;
  unsigned v[CHUNK / 256];
  #pragma unroll
  for (int j = 0; j < CHUNK / 256; j++){
    int i = j * 256 + tid;
    if (i < rem){ v[j] = packed[base + i]; atomicAdd(&lh[v[j] >> 24], 1); }
  }
  __syncthreads();
  lbase[tid] = lh[tid]; __syncthreads();
  incl_scan256(lbase, tid);
  int myExcl = tid ? lbase[tid - 1] : 0;
  __syncthreads();
  lbase[tid] = myExcl;
  lcur[tid] = myExcl;
  if (lh[tid] > 0) gpos[tid] = binBase_t + atomicAdd(&binOff[tid], lh[tid]);
  __syncthreads();
  #pragma unroll
  for (int j = 0; j < CHUNK / 256; j++){
    int i = j * 256 + tid;
    if (i < rem){
      int b = v[j] >> 24;
      int p = atomicAdd(&lcur[b], 1);
      buf[p] = v[j];
    }
  }
  __syncthreads();
  int cn = rem < CHUNK ? rem : CHUNK;
  for (int i = tid; i < cn; i += 256){
    unsigned u = buf[i];
    int b = u >> 24;
    binned[gpos[b] + (i - lbase[b])] = u;
  }
}

__device__ void group_body(char* smem, const unsigned* __restrict__ binned,
                           const int* __restrict__ binCnt, unsigned* __restrict__ sorted,
                           int* __restrict__ row_ptr, int N, int g){
  unsigned* A = (unsigned*)smem;            // GCAP
  unsigned* B = A + GCAP;                   // GCAP
  int* ib = (int*)(B + GCAP);
  int* sc = ib;        // 256
  int* h2 = ib + 256;
  int* rs = ib + 512;
  int* cur = ib + 768;
  int tid = threadIdx.x;
  int cg = binCnt[tid];
  sc[tid] = cg;
  h2[tid] = 0;
  __syncthreads();
  incl_scan256(sc, tid);
  int base = sc[g] - binCnt[g];
  int cnt = binCnt[g]; if (cnt > GCAP) cnt = GCAP;
  __syncthreads();
  for (int i = tid; i < cnt; i += 256){
    unsigned u = binned[base + i];
    A[i] = u;
    atomicAdd(&h2[(u >> 16) & 255], 1);
  }
  __syncthreads();
  rs[tid] = h2[tid]; __syncthreads();
  incl_scan256(rs, tid);
  int excl = tid ? rs[tid - 1] : 0;
  __syncthreads();
  rs[tid] = excl; cur[tid] = excl;
  int d = g * 256 + tid;
  if (d < N) row_ptr[d] = base + excl;
  __syncthreads();
  for (int i = tid; i < cnt; i += 256){
    unsigned u = A[i];
    int p = atomicAdd(&cur[(u >> 16) & 255], 1);
    B[p] = u;
  }
  __syncthreads();
  for (int i = tid; i < cnt; i += 256)
    sorted[base + i] = B[i];
}

// ---------- layer-1 GEMM body (MT=64, K=128, NC=128, 2 heads, 256 threads) ----------
// h1b bf16 store + fused attention coefficients, as before.
__device__ void gemm1_body(char* smem, const float* __restrict__ X,
                           const unsigned short* __restrict__ Wt,
                           const float* __restrict__ asrc, const float* __restrict__ adst,
                           unsigned short* __restrict__ Hb, float* __restrict__ aa,
                           int n_rows, int n0){
  const int KP = 136, CP = 132;
  unsigned short* xa = (unsigned short*)smem;   // [64][136]
  unsigned short* wl = xa + 64 * KP;            // [128][136]
  int tid = threadIdx.x;
  for (int idx = tid; idx < 64 * 32; idx += 256){
    int n = idx >> 5, k4 = idx & 31;
    float4 v = make_float4(0.f, 0.f, 0.f, 0.f);
    if (n0 + n < n_rows) v = *(const float4*)&X[(size_t)(n0 + n) * 128 + k4 * 4];
    ushort4 pk; pk.x = f2bf(v.x); pk.y = f2bf(v.y); pk.z = f2bf(v.z); pk.w = f2bf(v.w);
    *(ushort4*)&xa[n * KP + k4 * 4] = pk;
  }
  for (int idx = tid; idx < 128 * 16; idx += 256){
    int n = idx >> 4, k8 = idx & 15;
    uint4 v = *(const uint4*)&Wt[(size_t)n * 128 + k8 * 8];
    *(uint4*)&wl[n * KP + k8 * 8] = v;
  }
  __syncthreads();

  int lane = tid & 63, w = tid >> 6;
  int m = lane & 15, q = lane >> 4;
  f32x4 acc[4][2];
  #pragma unroll
  for (int i = 0; i < 4; i++)
    #pragma unroll
    for (int j = 0; j < 2; j++)
      #pragma unroll
      for (int r = 0; r < 4; r++) acc[i][j][r] = 0.f;
  #pragma unroll
  for (int ks = 0; ks < 4; ks++){
    bf16x8 bg[2];
    #pragma unroll
    for (int j = 0; j < 2; j++)
      bg[j] = *(const bf16x8*)&wl[((2 * w + j) * 16 + m) * KP + ks * 32 + q * 8];
    #pragma unroll
    for (int i = 0; i < 4; i++){
      bf16x8 af = *(const bf16x8*)&xa[(i * 16 + m) * KP + ks * 32 + q * 8];
      #pragma unroll
      for (int j = 0; j < 2; j++)
        acc[i][j] = __builtin_amdgcn_mfma_f32_16x16x32_bf16(af, bg[j], acc[i][j], 0, 0, 0);
    }
  }
  __syncthreads();
  float* C = (float*)smem;   // [64][132]
  #pragma unroll
  for (int i = 0; i < 4; i++)
    #pragma unroll
    for (int j = 0; j < 2; j++)
      #pragma unroll
      for (int r = 0; r < 4; r++)
        C[(i * 16 + q * 4 + r) * CP + (2 * w + j) * 16 + m] = acc[i][j][r];
  __syncthreads();

  int row = tid >> 2;
  int c0 = (tid & 3) * 32;
  int n = n0 + row;
  int head = (tid & 3) >> 1;
  float s_p = 0.f, d_p = 0.f;
  unsigned short hb[32];
  #pragma unroll
  for (int c = 0; c < 32; c += 4){
    f32x4 v = *(const f32x4*)&C[row * CP + c0 + c];
    #pragma unroll
    for (int u = 0; u < 4; u++){
      int ch = (c0 + c + u) & 63;
      s_p += v[u] * asrc[head * 64 + ch];
      d_p += v[u] * adst[head * 64 + ch];
      hb[c + u] = f2bf(v[u]);
    }
  }
  if (n < n_rows){
    #pragma unroll
    for (int c = 0; c < 32; c += 8){
      uint4 pk;
      pk.x = (unsigned)hb[c]     | ((unsigned)hb[c + 1] << 16);
      pk.y = (unsigned)hb[c + 2] | ((unsigned)hb[c + 3] << 16);
      pk.z = (unsigned)hb[c + 4] | ((unsigned)hb[c + 5] << 16);
      pk.w = (unsigned)hb[c + 6] | ((unsigned)hb[c + 7] << 16);
      *(uint4*)&Hb[(size_t)n * 128 + c0 + c] = pk;
    }
  }
  s_p += __shfl_xor(s_p, 1);
  d_p += __shfl_xor(d_p, 1);
  if ((tid & 1) == 0 && n < n_rows){
    aa[(size_t)n * 4 + head]     = s_p;
    aa[(size_t)n * 4 + 2 + head] = d_p;
  }
}

// ---------- combined launches: sort phases overlapped with gemm1 halves ----------

__global__ __launch_bounds__(256) void sort_gemm_a(const unsigned* __restrict__ packed, int E,
    const int* __restrict__ binCnt, int* __restrict__ binOff, unsigned* __restrict__ binned,
    int NS, const float* __restrict__ X, const unsigned short* __restrict__ W1t,
    const float* __restrict__ asrc1, const float* __restrict__ adst1,
    unsigned short* __restrict__ h1b, float* __restrict__ aa1, int n_rows){
  __shared__ char smem[SMEM_UNION];
  int bx = blockIdx.x;
  if (bx < NS){
    scatter_body(smem, packed, E, binCnt, binOff, binned, bx);
  } else {
    gemm1_body(smem, X, W1t, asrc1, adst1, h1b, aa1, n_rows, (bx - NS) * 64);
  }
}

__global__ __launch_bounds__(256) void sort_gemm_b(const unsigned* __restrict__ binned,
    const int* __restrict__ binCnt, unsigned* __restrict__ sorted, int* __restrict__ row_ptr,
    int N, int NS, int gofs, const float* __restrict__ X, const unsigned short* __restrict__ W1t,
    const float* __restrict__ asrc1, const float* __restrict__ adst1,
    unsigned short* __restrict__ h1b, float* __restrict__ aa1, int n_rows){
  __shared__ char smem[SMEM_UNION];
  int bx = blockIdx.x;
  if (bx < NS){
    group_body(smem, binned, binCnt, sorted, row_ptr, N, bx);
  } else {
    gemm1_body(smem, X, W1t, asrc1, adst1, h1b, aa1, n_rows, (gofs + bx - NS) * 64);
  }
}

// ---------- prep: pack+hist + W conversion + row_ptr seed ----------

__global__ __launch_bounds__(256) void prep(const int* __restrict__ ei, int E, int NBLK,
                                            unsigned* __restrict__ packed,
                                            int* __restrict__ binCnt,
                                            const float* __restrict__ W1,
                                            const float* __restrict__ W2,
                                            unsigned short* __restrict__ W1t,
                                            unsigned short* __restrict__ W2t,
                                            int* __restrict__ row_ptr, int N){
  int tid = threadIdx.x;
  if ((int)blockIdx.x < NBLK){
    __shared__ int lh[256];
    lh[tid] = 0; __syncthreads();
    int base = blockIdx.x * CHUNK;
    #pragma unroll
    for (int j = 0; j < CHUNK / 256; j++){
      int e = base + j * 256 + tid;
      if (e < E){
        unsigned s = (unsigned)ei[e];
        unsigned d = (unsigned)ei[E + e];
        packed[e] = (d << 16) | s;
        atomicAdd(&lh[d >> 8], 1);
      }
    }
    __syncthreads();
    if (lh[tid] > 0) atomicAdd(&binCnt[tid], lh[tid]);
  } else {
    int t = (blockIdx.x - NBLK) * 256 + tid;
    if (t < 128 * 128){
      int n = t >> 7, k = t & 127;
      W1t[n * 128 + k] = f2bf(W1[k * 128 + n]);
    }
    int t2 = t - 128 * 128;
    if (t2 >= 0 && t2 < 64 * 64){
      int n = t2 >> 6, k = t2 & 63;
      W2t[n * 64 + k] = f2bf(W2[k * 64 + n]);
    }
    if (t == 0) row_ptr[N] = E;
  }
}

// ---------- layer-2 GEMM (MFMA bf16, M-tile 128, 512 threads) ----------

template<int K, int NC, int HEADS>
__global__ __launch_bounds__(512) void gemm_mfma(const float* __restrict__ X,
    const unsigned short* __restrict__ Wt, const float* __restrict__ asrc,
    const float* __restrict__ adst, unsigned short* __restrict__ Hb,
    float* __restrict__ aa, int n_rows)
{
  constexpr int MT = 128;
  constexpr int KP = K + 8;
  constexpr int CP = NC + 4;
  constexpr int MF = MT / 16;
  constexpr int NFt = NC / 16;
  constexpr int WPN = 8 / NFt;
  constexpr int MFW = MF / WPN;
  constexpr unsigned SM1 = (unsigned)(MT + NC) * KP * 2;
  constexpr unsigned SM2 = (unsigned)MT * CP * 4;
  __shared__ char smem[SM1 > SM2 ? SM1 : SM2];
  unsigned short* xa = (unsigned short*)smem;
  unsigned short* wl = xa + MT * KP;
  int tid = threadIdx.x;
  int n0 = blockIdx.x * MT;

  for (int idx = tid; idx < MT * (K / 4); idx += 512){
    int n = idx / (K / 4), k4 = idx % (K / 4);
    float4 v = make_float4(0.f, 0.f, 0.f, 0.f);
    if (n0 + n < n_rows) v = *(const float4*)&X[(size_t)(n0 + n) * K + k4 * 4];
    ushort4 pk; pk.x = f2bf(v.x); pk.y = f2bf(v.y); pk.z = f2bf(v.z); pk.w = f2bf(v.w);
    *(ushort4*)&xa[n * KP + k4 * 4] = pk;
  }
  for (int idx = tid; idx < NC * (K / 8); idx += 512){
    int n = idx / (K / 8), k8 = idx % (K / 8);
    uint4 v = *(const uint4*)&Wt[(size_t)n * K + k8 * 8];
    *(uint4*)&wl[n * KP + k8 * 8] = v;
  }
  __syncthreads();

  int lane = tid & 63, w = tid >> 6;
  int m = lane & 15, q = lane >> 4;
  int nf = w % NFt;
  int mseg = w / NFt;
  f32x4 acc[MFW];
  #pragma unroll
  for (int i = 0; i < MFW; i++)
    #pragma unroll
    for (int r = 0; r < 4; r++) acc[i][r] = 0.f;

  #pragma unroll
  for (int ks = 0; ks < K / 32; ks++){
    bf16x8 bg = *(const bf16x8*)&wl[(nf * 16 + m) * KP + ks * 32 + q * 8];
    #pragma unroll
    for (int i = 0; i < MFW; i++){
      bf16x8 af = *(const bf16x8*)&xa[((mseg * MFW + i) * 16 + m) * KP + ks * 32 + q * 8];
      acc[i] = __builtin_amdgcn_mfma_f32_16x16x32_bf16(af, bg, acc[i], 0, 0, 0);
    }
  }
  __syncthreads();
  float* C = (float*)smem;
  #pragma unroll
  for (int i = 0; i < MFW; i++)
    #pragma unroll
    for (int r = 0; r < 4; r++)
      C[((mseg * MFW + i) * 16 + q * 4 + r) * CP + nf * 16 + m] = acc[i][r];
  __syncthreads();

  constexpr int CH = NC / 4;
  int row = tid >> 2;
  int c0 = (tid & 3) * CH;
  int n = n0 + row;
  int head = (HEADS == 2) ? (c0 >> 6) : 0;
  float s_p = 0.f, d_p = 0.f;
  unsigned short hb[CH];
  #pragma unroll
  for (int c = 0; c < CH; c += 4){
    f32x4 v = *(const f32x4*)&C[row * CP + c0 + c];
    #pragma unroll
    for (int u = 0; u < 4; u++){
      int ch = (c0 + c + u) & 63;
      s_p += v[u] * asrc[head * 64 + ch];
      d_p += v[u] * adst[head * 64 + ch];
      hb[c + u] = f2bf(v[u]);
    }
  }
  if (n < n_rows){
    #pragma unroll
    for (int c = 0; c < CH; c += 8){
      uint4 pk;
      pk.x = (unsigned)hb[c]     | ((unsigned)hb[c + 1] << 16);
      pk.y = (unsigned)hb[c + 2] | ((unsigned)hb[c + 3] << 16);
      pk.z = (unsigned)hb[c + 4] | ((unsigned)hb[c + 5] << 16);
      pk.w = (unsigned)hb[c + 6] | ((unsigned)hb[c + 7] << 16);
      *(uint4*)&Hb[(size_t)n * NC + c0 + c] = pk;
    }
  }
  s_p += __shfl_xor(s_p, 1);
  d_p += __shfl_xor(d_p, 1);
  if (HEADS == 2){
    if ((tid & 1) == 0 && n < n_rows){
      aa[(size_t)n * 4 + head]     = s_p;
      aa[(size_t)n * 4 + 2 + head] = d_p;
    }
  } else {
    s_p += __shfl_xor(s_p, 2);
    d_p += __shfl_xor(d_p, 2);
    if ((tid & 3) == 0 && n < n_rows){
      aa[(size_t)n * 2]     = s_p;
      aa[(size_t)n * 2 + 1] = d_p;
    }
  }
}

// ---------- softmax + aggregation (CSR, round-5 form) ----------

__global__ void agg_layer1(const int* __restrict__ row_ptr, const unsigned* __restrict__ sorted,
                           const float* __restrict__ aa, const unsigned short* __restrict__ h1b,
                           const float* __restrict__ b1, float* __restrict__ x1, int n_nodes){
  int d = (blockIdx.x * blockDim.x + threadIdx.x) >> 6;
  int lane = threadIdx.x & 63;
  if (d >= n_nodes) return;
  int rp0 = row_ptr[d];
  int deg = row_ptr[d + 1] - rp0;
  float2 adv = *(const float2*)&aa[d * 4 + 2];
  int s = -1;
  if (lane < deg) s = (int)(sorted[rp0 + lane] & 0xffffu);
  else if (lane == deg) s = d;
  float e0 = -INFINITY, e1 = -INFINITY;
  if (s >= 0){
    float2 asv = *(const float2*)&aa[s * 4];
    float t0 = asv.x + adv.x;
    float t1 = asv.y + adv.y;
    e0 = t0 >= 0.f ? t0 : NEG_SLOPE * t0;
    e1 = t1 >= 0.f ? t1 : NEG_SLOPE * t1;
  }
  float m0 = wmax(e0), m1 = wmax(e1);
  float p0 = (s >= 0) ? __expf(e0 - m0) : 0.f;
  float p1 = (s >= 0) ? __expf(e1 - m1) : 0.f;
  float al0 = p0 / (wsum(p0) + 1e-16f);
  float al1 = p1 / (wsum(p1) + 1e-16f);
  int ne = deg + 1;
  int g = lane >> 4, c = lane & 15;
  v2f acc[4] = {{0.f,0.f},{0.f,0.f},{0.f,0.f},{0.f,0.f}};
  #pragma unroll 2
  for (int j0 = 0; j0 < ne; j0 += 4){
    int j = j0 + g;
    int sj = __shfl(s, j);
    float a0 = __shfl(al0, j);
    float a1 = __shfl(al1, j);
    if (j < ne){
      uint4 v = ((const uint4*)(h1b + (size_t)sj * 128))[c];
      float a = (c < 8) ? a0 : a1;
      v2f av = {a, a};
      acc[0] = av * up2(v.x) + acc[0];
      acc[1] = av * up2(v.y) + acc[1];
      acc[2] = av * up2(v.z) + acc[2];
      acc[3] = av * up2(v.w) + acc[3];
    }
  }
  float accf[8] = {acc[0][0], acc[0][1], acc[1][0], acc[1][1],
                   acc[2][0], acc[2][1], acc[3][0], acc[3][1]};
  #pragma unroll
  for (int i = 0; i < 8; i++){
    accf[i] += __shfl_xor(accf[i], 16);
    accf[i] += __shfl_xor(accf[i], 32);
  }
  float outv[8];
  #pragma unroll
  for (int i = 0; i < 8; i++){
    float o = __shfl_xor(accf[i], 8);
    outv[i] = 0.5f * (accf[i] + o);
  }
  if (g == 0 && c < 8){
    float r[8];
    #pragma unroll
    for (int i = 0; i < 8; i++){
      float v = outv[i] + b1[c * 8 + i];
      r[i] = v > 0.f ? v : expm1f(v);
    }
    float* p = &x1[(size_t)d * 64 + c * 8];
    *(float4*)p       = make_float4(r[0], r[1], r[2], r[3]);
    *(float4*)(p + 4) = make_float4(r[4], r[5], r[6], r[7]);
  }
}

__global__ void agg_layer2(const int* __restrict__ row_ptr, const unsigned* __restrict__ sorted,
                           const float* __restrict__ aa, const unsigned short* __restrict__ h2b,
                           const float* __restrict__ b2, float* __restrict__ out, int n_nodes){
  int d = (blockIdx.x * blockDim.x + threadIdx.x) >> 6;
  int lane = threadIdx.x & 63;
  if (d >= n_nodes) return;
  int rp0 = row_ptr[d];
  int deg = row_ptr[d + 1] - rp0;
  float ad = aa[d * 2 + 1];
  int s = -1;
  if (lane < deg) s = (int)(sorted[rp0 + lane] & 0xffffu);
  else if (lane == deg) s = d;
  float e = -INFINITY;
  if (s >= 0){
    float t = aa[s * 2 + 0] + ad;
    e = t >= 0.f ? t : NEG_SLOPE * t;
  }
  float m = wmax(e);
  float p = (s >= 0) ? __expf(e - m) : 0.f;
  float al = p / (wsum(p) + 1e-16f);
  int ne = deg + 1;
  int g = lane >> 3, c = lane & 7;
  v2f acc[4] = {{0.f,0.f},{0.f,0.f},{0.f,0.f},{0.f,0.f}};
  #pragma unroll 2
  for (int j0 = 0; j0 < ne; j0 += 8){
    int j = j0 + g;
    int sj = __shfl(s, j);
    float a = __shfl(al, j);
    if (j < ne){
      uint4 v = ((const uint4*)(h2b + (size_t)sj * 64))[c];
      v2f av = {a, a};
      acc[0] = av * up2(v.x) + acc[0];
      acc[1] = av * up2(v.y) + acc[1];
      acc[2] = av * up2(v.z) + acc[2];
      acc[3] = av * up2(v.w) + acc[3];
    }
  }
  float accf[8] = {acc[0][0], acc[0][1], acc[1][0], acc[1][1],
                   acc[2][0], acc[2][1], acc[3][0], acc[3][1]};
  #pragma unroll
  for (int i = 0; i < 8; i++){
    accf[i] += __shfl_xor(accf[i], 8);
    accf[i] += __shfl_xor(accf[i], 16);
    accf[i] += __shfl_xor(accf[i], 32);
  }
  if (lane < 8){
    float r[8];
    #pragma unroll
    for (int i = 0; i < 8; i++) r[i] = accf[i] + b2[lane * 8 + i];
    float* q = &out[(size_t)d * 64 + lane * 8];
    *(float4*)q       = make_float4(r[0], r[1], r[2], r[3]);
    *(float4*)(q + 4) = make_float4(r[4], r[5], r[6], r[7]);
  }
}

extern "C" void kernel_launch(void* const* d_in, const int* in_sizes, int n_in,
                              void* d_out, int out_size, void* d_ws, size_t ws_size,
                              hipStream_t stream){
  const float* x     = (const float*)d_in[0];
  const int*   ei    = (const int*)d_in[1];
  const float* W1    = (const float*)d_in[2];
  const float* asrc1 = (const float*)d_in[3];
  const float* adst1 = (const float*)d_in[4];
  const float* b1    = (const float*)d_in[5];
  const float* W2    = (const float*)d_in[6];
  const float* asrc2 = (const float*)d_in[7];
  const float* adst2 = (const float*)d_in[8];
  const float* b2    = (const float*)d_in[9];
  float* out = (float*)d_out;
  int N = in_sizes[0] / IN_DIM;   // 50000 (< 65536 for 16-bit packing)
  int E = in_sizes[1] / 2;
  int NG = (N + 255) >> 8;                  // coarse bins (196)
  int NBLK = (E + CHUNK - 1) / CHUNK;       // scatter blocks (196)
  int ngrp = (N + 3) / 4;
  int GT = (N + 63) / 64;                   // total 64-row gemm1 blocks (782)
  int GA = GT / 2;                          // first half with scatter
  int GB = GT - GA;                         // second half with group_sort

  char* p = (char*)d_ws;
  unsigned short* h1b = (unsigned short*)p;  p += (size_t)N * 128 * 2;
  unsigned short* h2b = (unsigned short*)p;  p += (size_t)N * 64 * 2;
  float* x1  = (float*)p;                    p += (size_t)N * 64 * 4;
  float* aa1 = (float*)p;                    p += (size_t)N * 4 * 4;
  float* aa2 = (float*)p;                    p += (size_t)N * 2 * 4;
  unsigned* packed = (unsigned*)p;           p += (size_t)E * 4;
  unsigned* binned = (unsigned*)p;           p += (size_t)E * 4;
  unsigned* sorted = (unsigned*)p;           p += (size_t)E * 4;
  int* row_ptr   = (int*)p;                  p += (size_t)(N + 1) * 4;
  int* binCnt    = (int*)p;                  p += 256 * 4;
  int* binOff    = (int*)p;                  p += 256 * 4;
  unsigned short* W1t = (unsigned short*)p;  p += 128 * 128 * 2;
  unsigned short* W2t = (unsigned short*)p;

  hipMemsetAsync(binCnt, 0, 512 * sizeof(int), stream);   // binCnt + binOff
  prep<<<NBLK + 80, 256, 0, stream>>>(ei, E, NBLK, packed, binCnt,
                                      W1, W2, W1t, W2t, row_ptr, N);
  sort_gemm_a<<<NBLK + GA, 256, 0, stream>>>(packed, E, binCnt, binOff, binned,
                                             NBLK, x, W1t, asrc1, adst1, h1b, aa1, N);
  sort_gemm_b<<<NG + GB, 256, 0, stream>>>(binned, binCnt, sorted, row_ptr, N,
                                           NG, GA, x, W1t, asrc1, adst1, h1b, aa1, N);
  agg_layer1<<<ngrp, 256, 0, stream>>>(row_ptr, sorted, aa1, h1b, b1, x1, N);
  gemm_mfma<64, 64, 1><<<(N + 127) / 128, 512, 0, stream>>>(
      x1, W2t, asrc2, adst2, h2b, aa2, N);
  agg_layer2<<<ngrp, 256, 0, stream>>>(row_ptr, sorted, aa2, h2b, b2, out, N);
}